// Round 4
// baseline (787.304 us; speedup 1.0000x reference)
//
#include <hip/hip_runtime.h>
#include <hip/hip_bf16.h>

// GAT via on-device bucketed CSR. h = x@W^T stored bf16; att coeffs fused into
// k_lin epilogue (fp32 exact); CSR by dst built with bucket counting-sort;
// wave-per-dst aggregation gathers bf16 h and atomically pools into
// pooled[batch[n]]; BN over graphs; FC 128->32.  H=2 heads x C=64.
// Softmax max-shift skipped (shift-invariant; |e|<~10, exp safe in fp32).

static __device__ __forceinline__ float bf2f(unsigned short u) {
    union { unsigned int i; float f; } c; c.i = ((unsigned int)u) << 16; return c.f;
}

// ---------------- zero fill ----------------
__global__ void k_zero(float* __restrict__ p, long long n) {
    long long i = (long long)blockIdx.x * blockDim.x + threadIdx.x;
    long long stride = (long long)gridDim.x * blockDim.x;
    for (; i < n; i += stride) p[i] = 0.f;
}

// ------- h = x @ W^T -> bf16 h2; fused a_src/a_dst (fp32, wave-reduced) -------
__global__ __launch_bounds__(256) void k_lin(const float* __restrict__ x,
                                             const float* __restrict__ w,
                                             const float* __restrict__ att_s,
                                             const float* __restrict__ att_d,
                                             unsigned short* __restrict__ h2,
                                             float* __restrict__ asrc,
                                             float* __restrict__ adst, int N) {
    __shared__ float wl[128 * 64];
    __shared__ float xl[32 * 128];
    const int t = threadIdx.x;
    const int row0 = blockIdx.x * 32;

    for (int i = t; i < 32 * 128; i += 256) {
        int r = row0 + (i >> 7);
        xl[i] = (r < N) ? x[(long long)r * 128 + (i & 127)] : 0.f;
    }

    const int j = t & 127;           // output col = head*64 + c
    const int rbase = (t >> 7) * 16; // rows rbase..rbase+15
    float acc[16];
#pragma unroll
    for (int r = 0; r < 16; ++r) acc[r] = 0.f;

    for (int half = 0; half < 2; ++half) {
        __syncthreads();
        for (int i = t; i < 128 * 64; i += 256) {
            int jj = i >> 6, kk = i & 63;
            wl[jj * 64 + ((kk + jj) & 63)] = w[jj * 128 + half * 64 + kk];
        }
        __syncthreads();
        const int kb = half * 64;
#pragma unroll 4
        for (int kk = 0; kk < 64; ++kk) {
            float wv = wl[j * 64 + ((kk + j) & 63)];
            int k = kb + kk;
#pragma unroll
            for (int r = 0; r < 16; ++r)
                acc[r] = fmaf(xl[(rbase + r) * 128 + k], wv, acc[r]);
        }
    }

    // store bf16 h
    for (int r = 0; r < 16; ++r) {
        int row = row0 + rbase + r;
        if (row < N) h2[(long long)row * 128 + j] = (unsigned short)(__builtin_bit_cast(unsigned int, acc[r]) >> 16) + ((__builtin_bit_cast(unsigned int, acc[r]) >> 15) & 1);
    }

    // fused attention coefficients: each wave holds one head (64 channels) x 16 rows
    const int head = (t >> 6) & 1;   // wave0:head0, wave1:head1 (rbase 0); waves 2,3 same for rbase 16
    const float as = att_s[j];
    const float ad = att_d[j];
#pragma unroll
    for (int r = 0; r < 16; ++r) {
        float ps = acc[r] * as;
        float pd = acc[r] * ad;
#pragma unroll
        for (int off = 32; off; off >>= 1) {
            ps += __shfl_xor(ps, off);
            pd += __shfl_xor(pd, off);
        }
        int row = row0 + rbase + r;
        if ((t & 63) == 0 && row < N) {
            asrc[row * 2 + head] = ps;
            adst[row * 2 + head] = pd;
        }
    }
}

// ---------------- CSR build: histogram of dst ----------------
__global__ void k_hist(const int* __restrict__ ei, int E, int* __restrict__ deg) {
    int i = blockIdx.x * blockDim.x + threadIdx.x;
    int stride = gridDim.x * blockDim.x;
    for (; i < E; i += stride) atomicAdd(&deg[ei[E + i]], 1);
}

// ---------------- CSR build: exclusive scan (1 block, 1024 thr) ----------------
__global__ __launch_bounds__(1024) void k_scan(const int* __restrict__ deg,
                                               int* __restrict__ rowptr, int N) {
    __shared__ int part[1024];
    int t = threadIdx.x;
    int chunk = (N + 1023) >> 10;
    int lo = t * chunk, hi = min(lo + chunk, N);
    int s = 0;
    for (int i = lo; i < hi; ++i) s += deg[i];
    part[t] = s;
    __syncthreads();
    for (int off = 1; off < 1024; off <<= 1) {
        int v = (t >= off) ? part[t - off] : 0;
        __syncthreads();
        part[t] += v;
        __syncthreads();
    }
    int base = (t == 0) ? 0 : part[t - 1];
    for (int i = lo; i < hi; ++i) { rowptr[i] = base; base += deg[i]; }
    if (t == 1023) rowptr[N] = part[1023];
}

// ------- CSR build: scatter into 64-node buckets (packed src|d_local) -------
// bucket base in csr space = rowptr[b*64] (buckets are aligned dst ranges).
__global__ void k_bscatter(const int* __restrict__ ei, int E,
                           const int* __restrict__ rowptr,
                           int* __restrict__ bcursor,
                           unsigned int* __restrict__ stage) {
    int i = blockIdx.x * blockDim.x + threadIdx.x;
    int stride = gridDim.x * blockDim.x;
    for (; i < E; i += stride) {
        int s = ei[i];
        int d = ei[E + i];
        int b = d >> 6;
        int pos = rowptr[b << 6] + atomicAdd(&bcursor[b], 1);
        stage[pos] = ((unsigned int)(d & 63) << 26) | (unsigned int)s;
    }
}

// ------- CSR build: per-bucket counting sort (block per bucket, LDS cursors) ----
__global__ __launch_bounds__(256) void k_bsort(const int* __restrict__ rowptr,
                                               const unsigned int* __restrict__ stage,
                                               int* __restrict__ csr, int N) {
    int b = blockIdx.x;
    int node0 = b << 6;
    int nloc = min(64, N - node0);
    __shared__ int rp[65];
    __shared__ int lcur[64];
    int t = threadIdx.x;
    if (t <= nloc) rp[t] = rowptr[node0 + t];
    if (t < 64) lcur[t] = 0;
    __syncthreads();
    int beg = rp[0], end = rp[nloc];
    for (int i = beg + t; i < end; i += 256) {
        unsigned int w = stage[i];
        int dl = (int)(w >> 26);
        int pos = rp[dl] + atomicAdd(&lcur[dl], 1);
        csr[pos] = (int)(w & 0x03FFFFFFu);
    }
}

// ------- aggregation: wave per dst node, fused graph-pool atomics -------
// out[n] = (w_self*h[n] + sum_e w_e*h[src_e]) / (w_self + sum_e w_e) + bias
// pooled[batch[n]] += out[n]
__global__ __launch_bounds__(256) void k_agg(const int* __restrict__ rowptr,
                                             const int* __restrict__ csr_src,
                                             const unsigned short* __restrict__ h2,
                                             const float* __restrict__ asrc,
                                             const float* __restrict__ adst,
                                             const float* __restrict__ bias,
                                             const int* __restrict__ batch,
                                             float* __restrict__ pooled, int N) {
    int n = __builtin_amdgcn_readfirstlane(blockIdx.x * 4 + (threadIdx.x >> 6));
    int lane = threadIdx.x & 63;
    if (n >= N) return;
    float ad0 = adst[n * 2], ad1 = adst[n * 2 + 1];
    // self-loop
    float e0 = asrc[n * 2] + ad0;     e0 = e0 > 0.f ? e0 : 0.2f * e0;
    float e1 = asrc[n * 2 + 1] + ad1; e1 = e1 > 0.f ? e1 : 0.2f * e1;
    float w0 = __expf(e0), w1 = __expf(e1);

    unsigned int v = *(const unsigned int*)(h2 + (long long)n * 128 + lane * 2);
    float wsel = (lane < 32) ? w0 : w1;
    float accx = wsel * bf2f((unsigned short)(v & 0xffff));
    float accy = wsel * bf2f((unsigned short)(v >> 16));
    float s0 = w0, s1 = w1;

    int beg = rowptr[n], end = rowptr[n + 1];
    for (int e = beg; e < end; ++e) {
        int s = __builtin_amdgcn_readfirstlane(csr_src[e]);
        float f0 = asrc[s * 2] + ad0;     f0 = f0 > 0.f ? f0 : 0.2f * f0;
        float f1 = asrc[s * 2 + 1] + ad1; f1 = f1 > 0.f ? f1 : 0.2f * f1;
        float u0 = __expf(f0), u1 = __expf(f1);
        unsigned int vv = *(const unsigned int*)(h2 + (long long)s * 128 + lane * 2);
        float u = (lane < 32) ? u0 : u1;
        accx = fmaf(u, bf2f((unsigned short)(vv & 0xffff)), accx);
        accy = fmaf(u, bf2f((unsigned short)(vv >> 16)), accy);
        s0 += u0; s1 += u1;
    }
    float sdiv = (lane < 32) ? s0 : s1;
    int j0 = lane * 2;
    float2 bv = *(const float2*)(bias + j0);
    float o0 = accx / sdiv + bv.x;
    float o1 = accy / sdiv + bv.y;
    int g = batch[n];
    atomicAdd(&pooled[g * 128 + j0], o0);
    atomicAdd(&pooled[g * 128 + j0 + 1], o1);
}

// ---------------- batchnorm stats over G graphs ----------------
__global__ __launch_bounds__(512) void k_bnstat(const float* __restrict__ pooled,
                                                const float* __restrict__ gamma,
                                                const float* __restrict__ beta,
                                                float* __restrict__ scale,
                                                float* __restrict__ shift, int G) {
    __shared__ float ls[512], lq[512];
    int t = threadIdx.x;
    int j = t & 127, q = t >> 7;
    int per = G >> 2;
    float sum = 0.f, sq = 0.f;
    for (int g = q * per; g < (q + 1) * per; ++g) {
        float v = pooled[g * 128 + j];
        sum += v; sq += v * v;
    }
    ls[t] = sum; lq[t] = sq;
    __syncthreads();
    if (t < 128) {
        sum = ls[t] + ls[t + 128] + ls[t + 256] + ls[t + 384];
        sq  = lq[t] + lq[t + 128] + lq[t + 256] + lq[t + 384];
        float mu = sum / (float)G;
        float var = sq / (float)G - mu * mu;
        float sc = gamma[t] * rsqrtf(var + 1e-5f);
        scale[t] = sc;
        shift[t] = beta[t] - mu * sc;
    }
}

// ---------------- norm + FC (block per graph) ----------------
__global__ __launch_bounds__(128) void k_fc(const float* __restrict__ pooled,
                                            const float* __restrict__ scale,
                                            const float* __restrict__ shift,
                                            const float* __restrict__ fcw,
                                            const float* __restrict__ fcb,
                                            float* __restrict__ out, int LAT) {
    __shared__ float nrm[128];
    int g = blockIdx.x;
    int t = threadIdx.x;
    nrm[t] = pooled[g * 128 + t] * scale[t] + shift[t];
    __syncthreads();
    if (t < LAT) {
        float acc = fcb[t];
#pragma unroll 8
        for (int j = 0; j < 128; ++j)
            acc = fmaf(nrm[j], fcw[t * 128 + j], acc);
        out[g * LAT + t] = acc;
    }
}

extern "C" void kernel_launch(void* const* d_in, const int* in_sizes, int n_in,
                              void* d_out, int out_size, void* d_ws, size_t ws_size,
                              hipStream_t stream) {
    const float* x     = (const float*)d_in[0];
    const int*   ei    = (const int*)d_in[1];
    const int*   batch = (const int*)d_in[2];
    const float* lin_w = (const float*)d_in[4];
    const float* att_s = (const float*)d_in[5];
    const float* att_d = (const float*)d_in[6];
    const float* bias  = (const float*)d_in[7];
    const float* gamma = (const float*)d_in[8];
    const float* beta  = (const float*)d_in[9];
    const float* fcw   = (const float*)d_in[10];
    const float* fcb   = (const float*)d_in[11];
    float* out = (float*)d_out;

    const int N   = in_sizes[2];
    const int E   = in_sizes[1] / 2;
    const int LAT = in_sizes[11];
    const int G   = out_size / LAT;
    const int NB  = (N + 63) >> 6;   // 64-node buckets

    char* ws = (char*)d_ws;
    unsigned short* h2 = (unsigned short*)ws; ws += (size_t)N * 128 * 2;
    float* asrc   = (float*)ws; ws += (size_t)N * 2 * 4;
    float* adst   = (float*)ws; ws += (size_t)N * 2 * 4;
    // zeroed region: deg | bcursor | pooled (contiguous words)
    int*   deg    = (int*)ws;   ws += (size_t)N * 4;
    int*   bcursor= (int*)ws;   ws += (size_t)NB * 4;
    float* pooled = (float*)ws; ws += (size_t)G * 128 * 4;
    float* scale  = (float*)ws; ws += 128 * 4;
    float* shift  = (float*)ws; ws += 128 * 4;
    int*   rowptr = (int*)ws;   ws += (size_t)(N + 1) * 4;
    unsigned int* stage = (unsigned int*)ws; ws += (size_t)E * 4;
    int*   csr    = (int*)ws;   ws += (size_t)E * 4;

    long long nzero = (long long)N + NB + (long long)G * 128;
    k_zero<<<512, 256, 0, stream>>>((float*)deg, nzero);

    k_lin<<<(N + 31) / 32, 256, 0, stream>>>(x, lin_w, att_s, att_d, h2, asrc, adst, N);
    k_hist<<<2048, 256, 0, stream>>>(ei, E, deg);
    k_scan<<<1, 1024, 0, stream>>>(deg, rowptr, N);
    k_bscatter<<<2048, 256, 0, stream>>>(ei, E, rowptr, bcursor, stage);
    k_bsort<<<NB, 256, 0, stream>>>(rowptr, stage, csr, N);
    k_agg<<<(N + 3) / 4, 256, 0, stream>>>(rowptr, csr, h2, asrc, adst, bias, batch, pooled, N);
    k_bnstat<<<1, 512, 0, stream>>>(pooled, gamma, beta, scale, shift, G);
    k_fc<<<G, 128, 0, stream>>>(pooled, scale, shift, fcw, fcb, out, LAT);
}

// Round 5
// 563.202 us; speedup vs baseline: 1.3979x; 1.3979x over previous
//
#include <hip/hip_runtime.h>
#include <hip/hip_bf16.h>

// GAT via on-device CSR (per-node cursor scatter). h = x@W^T stored bf16;
// att coeffs fused into k_lin epilogue (fp32 exact); wave-per-dst aggregation
// gathers bf16 h and atomically pools into pooled[batch[n]]; BN over graphs;
// FC 128->32.  H=2 heads x C=64.
// Softmax max-shift skipped (shift-invariant; |e|<~10, exp safe in fp32).

static __device__ __forceinline__ float bf2f(unsigned short u) {
    union { unsigned int i; float f; } c; c.i = ((unsigned int)u) << 16; return c.f;
}

// ---------------- zero fill ----------------
__global__ void k_zero(float* __restrict__ p, long long n) {
    long long i = (long long)blockIdx.x * blockDim.x + threadIdx.x;
    long long stride = (long long)gridDim.x * blockDim.x;
    for (; i < n; i += stride) p[i] = 0.f;
}

// ------- h = x @ W^T -> bf16 h2; fused a_src/a_dst (fp32, wave-reduced) -------
__global__ __launch_bounds__(256) void k_lin(const float* __restrict__ x,
                                             const float* __restrict__ w,
                                             const float* __restrict__ att_s,
                                             const float* __restrict__ att_d,
                                             unsigned short* __restrict__ h2,
                                             float* __restrict__ asrc,
                                             float* __restrict__ adst, int N) {
    __shared__ float wl[128 * 64];
    __shared__ float xl[32 * 128];
    const int t = threadIdx.x;
    const int row0 = blockIdx.x * 32;

    for (int i = t; i < 32 * 128; i += 256) {
        int r = row0 + (i >> 7);
        xl[i] = (r < N) ? x[(long long)r * 128 + (i & 127)] : 0.f;
    }

    const int j = t & 127;           // output col = head*64 + c
    const int rbase = (t >> 7) * 16; // rows rbase..rbase+15
    float acc[16];
#pragma unroll
    for (int r = 0; r < 16; ++r) acc[r] = 0.f;

    for (int half = 0; half < 2; ++half) {
        __syncthreads();
        for (int i = t; i < 128 * 64; i += 256) {
            int jj = i >> 6, kk = i & 63;
            wl[jj * 64 + ((kk + jj) & 63)] = w[jj * 128 + half * 64 + kk];
        }
        __syncthreads();
        const int kb = half * 64;
#pragma unroll 4
        for (int kk = 0; kk < 64; ++kk) {
            float wv = wl[j * 64 + ((kk + j) & 63)];
            int k = kb + kk;
#pragma unroll
            for (int r = 0; r < 16; ++r)
                acc[r] = fmaf(xl[(rbase + r) * 128 + k], wv, acc[r]);
        }
    }

    // store bf16 h (round-to-nearest-ish via bit trick)
    for (int r = 0; r < 16; ++r) {
        int row = row0 + rbase + r;
        if (row < N) {
            unsigned int bi = __builtin_bit_cast(unsigned int, acc[r]);
            h2[(long long)row * 128 + j] = (unsigned short)(bi >> 16) + ((bi >> 15) & 1);
        }
    }

    // fused attention coefficients: each wave holds one head (64 ch) x 16 rows
    const int head = (t >> 6) & 1;
    const float as = att_s[j];
    const float ad = att_d[j];
#pragma unroll
    for (int r = 0; r < 16; ++r) {
        float ps = acc[r] * as;
        float pd = acc[r] * ad;
#pragma unroll
        for (int off = 32; off; off >>= 1) {
            ps += __shfl_xor(ps, off);
            pd += __shfl_xor(pd, off);
        }
        int row = row0 + rbase + r;
        if ((t & 63) == 0 && row < N) {
            asrc[row * 2 + head] = ps;
            adst[row * 2 + head] = pd;
        }
    }
}

// ---------------- CSR build: histogram of dst ----------------
__global__ void k_hist(const int* __restrict__ ei, int E, int* __restrict__ deg) {
    int i = blockIdx.x * blockDim.x + threadIdx.x;
    int stride = gridDim.x * blockDim.x;
    for (; i < E; i += stride) atomicAdd(&deg[ei[E + i]], 1);
}

// ------ CSR build: exclusive scan; writes rowptr AND cursor(=rowptr) ------
__global__ __launch_bounds__(1024) void k_scan(const int* __restrict__ deg,
                                               int* __restrict__ rowptr,
                                               int* __restrict__ cursor, int N) {
    __shared__ int part[1024];
    int t = threadIdx.x;
    int chunk = (N + 1023) >> 10;
    int lo = t * chunk, hi = min(lo + chunk, N);
    int s = 0;
    for (int i = lo; i < hi; ++i) s += deg[i];
    part[t] = s;
    __syncthreads();
    for (int off = 1; off < 1024; off <<= 1) {
        int v = (t >= off) ? part[t - off] : 0;
        __syncthreads();
        part[t] += v;
        __syncthreads();
    }
    int base = (t == 0) ? 0 : part[t - 1];
    for (int i = lo; i < hi; ++i) {
        rowptr[i] = base;
        cursor[i] = base;
        base += deg[i];
    }
    if (t == 1023) rowptr[N] = part[1023];
}

// ------- CSR build: scatter srcs, per-node cursor (pos = atomic++) -------
__global__ void k_scatter(const int* __restrict__ ei, int E,
                          int* __restrict__ cursor, int* __restrict__ csr) {
    int i = blockIdx.x * blockDim.x + threadIdx.x;
    int stride = gridDim.x * blockDim.x;
    for (; i < E; i += stride) {
        int s = ei[i];
        int d = ei[E + i];
        int pos = atomicAdd(&cursor[d], 1);
        csr[pos] = s;
    }
}

// ------- aggregation: wave per dst node, fused graph-pool atomics -------
__global__ __launch_bounds__(256) void k_agg(const int* __restrict__ rowptr,
                                             const int* __restrict__ csr_src,
                                             const unsigned short* __restrict__ h2,
                                             const float* __restrict__ asrc,
                                             const float* __restrict__ adst,
                                             const float* __restrict__ bias,
                                             const int* __restrict__ batch,
                                             float* __restrict__ pooled, int N) {
    int n = __builtin_amdgcn_readfirstlane(blockIdx.x * 4 + (threadIdx.x >> 6));
    int lane = threadIdx.x & 63;
    if (n >= N) return;
    float ad0 = adst[n * 2], ad1 = adst[n * 2 + 1];
    // self-loop
    float e0 = asrc[n * 2] + ad0;     e0 = e0 > 0.f ? e0 : 0.2f * e0;
    float e1 = asrc[n * 2 + 1] + ad1; e1 = e1 > 0.f ? e1 : 0.2f * e1;
    float w0 = __expf(e0), w1 = __expf(e1);

    unsigned int v = *(const unsigned int*)(h2 + (long long)n * 128 + lane * 2);
    float wsel = (lane < 32) ? w0 : w1;
    float accx = wsel * bf2f((unsigned short)(v & 0xffff));
    float accy = wsel * bf2f((unsigned short)(v >> 16));
    float s0 = w0, s1 = w1;

    int beg = rowptr[n], end = rowptr[n + 1];
    for (int e = beg; e < end; ++e) {
        int s = __builtin_amdgcn_readfirstlane(csr_src[e]);
        float f0 = asrc[s * 2] + ad0;     f0 = f0 > 0.f ? f0 : 0.2f * f0;
        float f1 = asrc[s * 2 + 1] + ad1; f1 = f1 > 0.f ? f1 : 0.2f * f1;
        float u0 = __expf(f0), u1 = __expf(f1);
        unsigned int vv = *(const unsigned int*)(h2 + (long long)s * 128 + lane * 2);
        float u = (lane < 32) ? u0 : u1;
        accx = fmaf(u, bf2f((unsigned short)(vv & 0xffff)), accx);
        accy = fmaf(u, bf2f((unsigned short)(vv >> 16)), accy);
        s0 += u0; s1 += u1;
    }
    float sdiv = (lane < 32) ? s0 : s1;
    int j0 = lane * 2;
    float2 bv = *(const float2*)(bias + j0);
    float o0 = accx / sdiv + bv.x;
    float o1 = accy / sdiv + bv.y;
    int g = batch[n];
    atomicAdd(&pooled[g * 128 + j0], o0);
    atomicAdd(&pooled[g * 128 + j0 + 1], o1);
}

// ---------------- batchnorm stats over G graphs ----------------
__global__ __launch_bounds__(512) void k_bnstat(const float* __restrict__ pooled,
                                                const float* __restrict__ gamma,
                                                const float* __restrict__ beta,
                                                float* __restrict__ scale,
                                                float* __restrict__ shift, int G) {
    __shared__ float ls[512], lq[512];
    int t = threadIdx.x;
    int j = t & 127, q = t >> 7;
    int per = G >> 2;
    float sum = 0.f, sq = 0.f;
    for (int g = q * per; g < (q + 1) * per; ++g) {
        float v = pooled[g * 128 + j];
        sum += v; sq += v * v;
    }
    ls[t] = sum; lq[t] = sq;
    __syncthreads();
    if (t < 128) {
        sum = ls[t] + ls[t + 128] + ls[t + 256] + ls[t + 384];
        sq  = lq[t] + lq[t + 128] + lq[t + 256] + lq[t + 384];
        float mu = sum / (float)G;
        float var = sq / (float)G - mu * mu;
        float sc = gamma[t] * rsqrtf(var + 1e-5f);
        scale[t] = sc;
        shift[t] = beta[t] - mu * sc;
    }
}

// ---------------- norm + FC (block per graph) ----------------
__global__ __launch_bounds__(128) void k_fc(const float* __restrict__ pooled,
                                            const float* __restrict__ scale,
                                            const float* __restrict__ shift,
                                            const float* __restrict__ fcw,
                                            const float* __restrict__ fcb,
                                            float* __restrict__ out, int LAT) {
    __shared__ float nrm[128];
    int g = blockIdx.x;
    int t = threadIdx.x;
    nrm[t] = pooled[g * 128 + t] * scale[t] + shift[t];
    __syncthreads();
    if (t < LAT) {
        float acc = fcb[t];
#pragma unroll 8
        for (int j = 0; j < 128; ++j)
            acc = fmaf(nrm[j], fcw[t * 128 + j], acc);
        out[g * LAT + t] = acc;
    }
}

extern "C" void kernel_launch(void* const* d_in, const int* in_sizes, int n_in,
                              void* d_out, int out_size, void* d_ws, size_t ws_size,
                              hipStream_t stream) {
    const float* x     = (const float*)d_in[0];
    const int*   ei    = (const int*)d_in[1];
    const int*   batch = (const int*)d_in[2];
    const float* lin_w = (const float*)d_in[4];
    const float* att_s = (const float*)d_in[5];
    const float* att_d = (const float*)d_in[6];
    const float* bias  = (const float*)d_in[7];
    const float* gamma = (const float*)d_in[8];
    const float* beta  = (const float*)d_in[9];
    const float* fcw   = (const float*)d_in[10];
    const float* fcb   = (const float*)d_in[11];
    float* out = (float*)d_out;

    const int N   = in_sizes[2];
    const int E   = in_sizes[1] / 2;
    const int LAT = in_sizes[11];
    const int G   = out_size / LAT;

    char* ws = (char*)d_ws;
    unsigned short* h2 = (unsigned short*)ws; ws += (size_t)N * 128 * 2;
    float* asrc   = (float*)ws; ws += (size_t)N * 2 * 4;
    float* adst   = (float*)ws; ws += (size_t)N * 2 * 4;
    // zeroed region: deg | pooled (contiguous words)
    int*   deg    = (int*)ws;   ws += (size_t)N * 4;
    float* pooled = (float*)ws; ws += (size_t)G * 128 * 4;
    float* scale  = (float*)ws; ws += 128 * 4;
    float* shift  = (float*)ws; ws += 128 * 4;
    int*   rowptr = (int*)ws;   ws += (size_t)(N + 1) * 4;
    int*   cursor = (int*)ws;   ws += (size_t)N * 4;
    int*   csr    = (int*)ws;   ws += (size_t)E * 4;

    long long nzero = (long long)N + (long long)G * 128;
    k_zero<<<512, 256, 0, stream>>>((float*)deg, nzero);

    k_lin<<<(N + 31) / 32, 256, 0, stream>>>(x, lin_w, att_s, att_d, h2, asrc, adst, N);
    k_hist<<<2048, 256, 0, stream>>>(ei, E, deg);
    k_scan<<<1, 1024, 0, stream>>>(deg, rowptr, cursor, N);
    k_scatter<<<2048, 256, 0, stream>>>(ei, E, cursor, csr);
    k_agg<<<(N + 3) / 4, 256, 0, stream>>>(rowptr, csr, h2, asrc, adst, bias, batch, pooled, N);
    k_bnstat<<<1, 512, 0, stream>>>(pooled, gamma, beta, scale, shift, G);
    k_fc<<<G, 128, 0, stream>>>(pooled, scale, shift, fcw, fcb, out, LAT);
}

// Round 6
// 315.972 us; speedup vs baseline: 2.4917x; 1.7824x over previous
//
#include <hip/hip_runtime.h>
#include <hip/hip_bf16.h>

// GAT via 2-level bucketed CSR build (LDS-binned counting sort, no per-edge
// global atomics, line-coalesced writes). h = x@W^T stored bf16; att coeffs
// fused into k_lin epilogue (fp32 exact); wave-per-dst aggregation gathers
// bf16 h and atomically pools into pooled[batch[n]]; BN over graphs; FC.
// H=2 heads x C=64.  Softmax max-shift skipped (|e| small, exp safe in fp32).

#define BKT_SHIFT 8              // 256 nodes per bucket
#define BKT_MASK  255
#define BKT_CAP   14336          // LDS staging records in k_bsort (56 KB)
#define BIN_TILE  4096           // edges per block in k_b0/k_bin

static __device__ __forceinline__ float bf2f(unsigned short u) {
    union { unsigned int i; float f; } c; c.i = ((unsigned int)u) << 16; return c.f;
}

// ---------------- zero fill ----------------
__global__ void k_zero(float* __restrict__ p, long long n) {
    long long i = (long long)blockIdx.x * blockDim.x + threadIdx.x;
    long long stride = (long long)gridDim.x * blockDim.x;
    for (; i < n; i += stride) p[i] = 0.f;
}

// ------- h = x @ W^T -> bf16 h2; fused a_src/a_dst (fp32, wave-reduced) -------
__global__ __launch_bounds__(256) void k_lin(const float* __restrict__ x,
                                             const float* __restrict__ w,
                                             const float* __restrict__ att_s,
                                             const float* __restrict__ att_d,
                                             unsigned short* __restrict__ h2,
                                             float* __restrict__ asrc,
                                             float* __restrict__ adst, int N) {
    __shared__ float wl[128 * 64];
    __shared__ float xl[32 * 128];
    const int t = threadIdx.x;
    const int row0 = blockIdx.x * 32;

    for (int i = t; i < 32 * 128; i += 256) {
        int r = row0 + (i >> 7);
        xl[i] = (r < N) ? x[(long long)r * 128 + (i & 127)] : 0.f;
    }

    const int j = t & 127;           // output col = head*64 + c
    const int rbase = (t >> 7) * 16; // rows rbase..rbase+15
    float acc[16];
#pragma unroll
    for (int r = 0; r < 16; ++r) acc[r] = 0.f;

    for (int half = 0; half < 2; ++half) {
        __syncthreads();
        for (int i = t; i < 128 * 64; i += 256) {
            int jj = i >> 6, kk = i & 63;
            wl[jj * 64 + ((kk + jj) & 63)] = w[jj * 128 + half * 64 + kk];
        }
        __syncthreads();
        const int kb = half * 64;
#pragma unroll 4
        for (int kk = 0; kk < 64; ++kk) {
            float wv = wl[j * 64 + ((kk + j) & 63)];
            int k = kb + kk;
#pragma unroll
            for (int r = 0; r < 16; ++r)
                acc[r] = fmaf(xl[(rbase + r) * 128 + k], wv, acc[r]);
        }
    }

    for (int r = 0; r < 16; ++r) {
        int row = row0 + rbase + r;
        if (row < N) {
            unsigned int bi = __builtin_bit_cast(unsigned int, acc[r]);
            h2[(long long)row * 128 + j] = (unsigned short)(bi >> 16) + ((bi >> 15) & 1);
        }
    }

    const int head = (t >> 6) & 1;
    const float as = att_s[j];
    const float ad = att_d[j];
#pragma unroll
    for (int r = 0; r < 16; ++r) {
        float ps = acc[r] * as;
        float pd = acc[r] * ad;
#pragma unroll
        for (int off = 32; off; off >>= 1) {
            ps += __shfl_xor(ps, off);
            pd += __shfl_xor(pd, off);
        }
        int row = row0 + rbase + r;
        if ((t & 63) == 0 && row < N) {
            asrc[row * 2 + head] = ps;
            adst[row * 2 + head] = pd;
        }
    }
}

// ------- CSR build A: bucket histogram (one global atomic per block*bucket) ----
__global__ __launch_bounds__(256) void k_b0(const int* __restrict__ ei, int E,
                                            int* __restrict__ bcnt, int NB) {
    __shared__ int cnt[1024];
    int t = threadIdx.x;
    for (int i = t; i < 1024; i += 256) cnt[i] = 0;
    __syncthreads();
    int base = blockIdx.x * BIN_TILE;
    int end = min(base + BIN_TILE, E);
    for (int i = base + t; i < end; i += 256)
        atomicAdd(&cnt[ei[E + i] >> BKT_SHIFT], 1);
    __syncthreads();
    for (int b = t; b < NB; b += 256)
        if (cnt[b]) atomicAdd(&bcnt[b], cnt[b]);
}

// ------- CSR build B: scan bucket counts -> bases & cursors (1 block) ----------
__global__ __launch_bounds__(1024) void k_bscan(const int* __restrict__ bcnt,
                                                int* __restrict__ bbase,
                                                int* __restrict__ bcur, int NB, int E) {
    __shared__ int part[1024];
    int t = threadIdx.x;
    int v = (t < NB) ? bcnt[t] : 0;
    part[t] = v;
    __syncthreads();
    for (int off = 1; off < 1024; off <<= 1) {
        int u = (t >= off) ? part[t - off] : 0;
        __syncthreads();
        part[t] += u;
        __syncthreads();
    }
    if (t < NB) {
        int ex = part[t] - v;
        bbase[t] = ex;
        bcur[t] = ex;
    }
    if (t == 0) bbase[NB] = E;
}

// ------- CSR build C: bin edges into bucket runs (packed dl<<24|src) -----------
__global__ __launch_bounds__(256) void k_bin(const int* __restrict__ ei, int E,
                                             int* __restrict__ bcur,
                                             unsigned int* __restrict__ stage, int NB) {
    __shared__ int cnt[1024];
    __shared__ int gbase[1024];
    int t = threadIdx.x;
    for (int i = t; i < 1024; i += 256) cnt[i] = 0;
    __syncthreads();
    int base = blockIdx.x * BIN_TILE;
    int end = min(base + BIN_TILE, E);
    for (int i = base + t; i < end; i += 256)
        atomicAdd(&cnt[ei[E + i] >> BKT_SHIFT], 1);
    __syncthreads();
    for (int b = t; b < NB; b += 256) {
        int c = cnt[b];
        gbase[b] = c ? atomicAdd(&bcur[b], c) : 0;
    }
    __syncthreads();
    for (int i = t; i < 1024; i += 256) cnt[i] = 0;
    __syncthreads();
    for (int i = base + t; i < end; i += 256) {
        int s = ei[i];
        int d = ei[E + i];
        int b = d >> BKT_SHIFT;
        int off = atomicAdd(&cnt[b], 1);
        stage[gbase[b] + off] = ((unsigned int)(d & BKT_MASK) << 24) | (unsigned int)s;
    }
}

// ------- CSR build D: per-bucket counting sort; emits rowptr AND csr -----------
__global__ __launch_bounds__(256) void k_bsort(const int* __restrict__ bbase,
                                               const unsigned int* __restrict__ stage,
                                               int* __restrict__ rowptr,
                                               int* __restrict__ csr, int N, int E) {
    __shared__ int hist[256];
    __shared__ int sc[256];
    __shared__ int rp[256];
    __shared__ int lc[256];
    __shared__ int lout[BKT_CAP];
    int b = blockIdx.x;
    int node0 = b << BKT_SHIFT;
    int nloc = min(256, N - node0);
    int t = threadIdx.x;
    int bb = bbase[b], be = bbase[b + 1];
    hist[t] = 0; lc[t] = 0;
    __syncthreads();
    for (int i = bb + t; i < be; i += 256)
        atomicAdd(&hist[stage[i] >> 24], 1);
    __syncthreads();
    sc[t] = hist[t];
    __syncthreads();
    for (int off = 1; off < 256; off <<= 1) {
        int u = (t >= off) ? sc[t - off] : 0;
        __syncthreads();
        sc[t] += u;
        __syncthreads();
    }
    int rpg = bb + sc[t] - hist[t];   // global rowptr for node0+t
    rp[t] = rpg;
    if (t < nloc) rowptr[node0 + t] = rpg;
    if (b == 0 && t == 0) rowptr[N] = E;
    __syncthreads();
    for (int i = bb + t; i < be; i += 256) {
        unsigned int wrec = stage[i];
        int dl = (int)(wrec >> 24);
        int src = (int)(wrec & 0x00FFFFFFu);
        int pos = rp[dl] + atomicAdd(&lc[dl], 1);
        int rel = pos - bb;
        if (rel < BKT_CAP) lout[rel] = src;       // staged, coalesced flush below
        else csr[pos] = src;                       // overflow fallback (correct, slow)
    }
    __syncthreads();
    int cntb = be - bb; if (cntb > BKT_CAP) cntb = BKT_CAP;
    for (int i = t; i < cntb; i += 256) csr[bb + i] = lout[i];
}

// ------- aggregation: wave per dst node, fused graph-pool atomics -------
__global__ __launch_bounds__(256) void k_agg(const int* __restrict__ rowptr,
                                             const int* __restrict__ csr_src,
                                             const unsigned short* __restrict__ h2,
                                             const float* __restrict__ asrc,
                                             const float* __restrict__ adst,
                                             const float* __restrict__ bias,
                                             const int* __restrict__ batch,
                                             float* __restrict__ pooled, int N) {
    int n = __builtin_amdgcn_readfirstlane(blockIdx.x * 4 + (threadIdx.x >> 6));
    int lane = threadIdx.x & 63;
    if (n >= N) return;
    float ad0 = adst[n * 2], ad1 = adst[n * 2 + 1];
    float e0 = asrc[n * 2] + ad0;     e0 = e0 > 0.f ? e0 : 0.2f * e0;
    float e1 = asrc[n * 2 + 1] + ad1; e1 = e1 > 0.f ? e1 : 0.2f * e1;
    float w0 = __expf(e0), w1 = __expf(e1);

    unsigned int v = *(const unsigned int*)(h2 + (long long)n * 128 + lane * 2);
    float wsel = (lane < 32) ? w0 : w1;
    float accx = wsel * bf2f((unsigned short)(v & 0xffff));
    float accy = wsel * bf2f((unsigned short)(v >> 16));
    float s0 = w0, s1 = w1;

    int beg = rowptr[n], end = rowptr[n + 1];
    for (int e = beg; e < end; ++e) {
        int s = __builtin_amdgcn_readfirstlane(csr_src[e]);
        float f0 = asrc[s * 2] + ad0;     f0 = f0 > 0.f ? f0 : 0.2f * f0;
        float f1 = asrc[s * 2 + 1] + ad1; f1 = f1 > 0.f ? f1 : 0.2f * f1;
        float u0 = __expf(f0), u1 = __expf(f1);
        unsigned int vv = *(const unsigned int*)(h2 + (long long)s * 128 + lane * 2);
        float u = (lane < 32) ? u0 : u1;
        accx = fmaf(u, bf2f((unsigned short)(vv & 0xffff)), accx);
        accy = fmaf(u, bf2f((unsigned short)(vv >> 16)), accy);
        s0 += u0; s1 += u1;
    }
    float sdiv = (lane < 32) ? s0 : s1;
    int j0 = lane * 2;
    float2 bv = *(const float2*)(bias + j0);
    float o0 = accx / sdiv + bv.x;
    float o1 = accy / sdiv + bv.y;
    int g = batch[n];
    atomicAdd(&pooled[g * 128 + j0], o0);
    atomicAdd(&pooled[g * 128 + j0 + 1], o1);
}

// ---------------- batchnorm stats over G graphs ----------------
__global__ __launch_bounds__(512) void k_bnstat(const float* __restrict__ pooled,
                                                const float* __restrict__ gamma,
                                                const float* __restrict__ beta,
                                                float* __restrict__ scale,
                                                float* __restrict__ shift, int G) {
    __shared__ float ls[512], lq[512];
    int t = threadIdx.x;
    int j = t & 127, q = t >> 7;
    int per = G >> 2;
    float sum = 0.f, sq = 0.f;
    for (int g = q * per; g < (q + 1) * per; ++g) {
        float v = pooled[g * 128 + j];
        sum += v; sq += v * v;
    }
    ls[t] = sum; lq[t] = sq;
    __syncthreads();
    if (t < 128) {
        sum = ls[t] + ls[t + 128] + ls[t + 256] + ls[t + 384];
        sq  = lq[t] + lq[t + 128] + lq[t + 256] + lq[t + 384];
        float mu = sum / (float)G;
        float var = sq / (float)G - mu * mu;
        float sc = gamma[t] * rsqrtf(var + 1e-5f);
        scale[t] = sc;
        shift[t] = beta[t] - mu * sc;
    }
}

// ---------------- norm + FC (block per graph) ----------------
__global__ __launch_bounds__(128) void k_fc(const float* __restrict__ pooled,
                                            const float* __restrict__ scale,
                                            const float* __restrict__ shift,
                                            const float* __restrict__ fcw,
                                            const float* __restrict__ fcb,
                                            float* __restrict__ out, int LAT) {
    __shared__ float nrm[128];
    int g = blockIdx.x;
    int t = threadIdx.x;
    nrm[t] = pooled[g * 128 + t] * scale[t] + shift[t];
    __syncthreads();
    if (t < LAT) {
        float acc = fcb[t];
#pragma unroll 8
        for (int j = 0; j < 128; ++j)
            acc = fmaf(nrm[j], fcw[t * 128 + j], acc);
        out[g * LAT + t] = acc;
    }
}

extern "C" void kernel_launch(void* const* d_in, const int* in_sizes, int n_in,
                              void* d_out, int out_size, void* d_ws, size_t ws_size,
                              hipStream_t stream) {
    const float* x     = (const float*)d_in[0];
    const int*   ei    = (const int*)d_in[1];
    const int*   batch = (const int*)d_in[2];
    const float* lin_w = (const float*)d_in[4];
    const float* att_s = (const float*)d_in[5];
    const float* att_d = (const float*)d_in[6];
    const float* bias  = (const float*)d_in[7];
    const float* gamma = (const float*)d_in[8];
    const float* beta  = (const float*)d_in[9];
    const float* fcw   = (const float*)d_in[10];
    const float* fcb   = (const float*)d_in[11];
    float* out = (float*)d_out;

    const int N   = in_sizes[2];
    const int E   = in_sizes[1] / 2;
    const int LAT = in_sizes[11];
    const int G   = out_size / LAT;
    const int NB  = (N + 255) >> BKT_SHIFT;   // 256-node buckets (NB <= 1024)

    char* ws = (char*)d_ws;
    unsigned short* h2 = (unsigned short*)ws; ws += (size_t)N * 128 * 2;
    float* asrc   = (float*)ws; ws += (size_t)N * 2 * 4;
    float* adst   = (float*)ws; ws += (size_t)N * 2 * 4;
    // zeroed region: bcnt | pooled (contiguous words)
    int*   bcnt   = (int*)ws;   ws += (size_t)NB * 4;
    float* pooled = (float*)ws; ws += (size_t)G * 128 * 4;
    float* scale  = (float*)ws; ws += 128 * 4;
    float* shift  = (float*)ws; ws += 128 * 4;
    int*   bbase  = (int*)ws;   ws += (size_t)(NB + 1) * 4;
    int*   bcur   = (int*)ws;   ws += (size_t)NB * 4;
    int*   rowptr = (int*)ws;   ws += (size_t)(N + 1) * 4;
    unsigned int* stage = (unsigned int*)ws; ws += (size_t)E * 4;
    int*   csr    = (int*)ws;   ws += (size_t)E * 4;

    long long nzero = (long long)NB + (long long)G * 128;
    k_zero<<<256, 256, 0, stream>>>((float*)bcnt, nzero);

    k_lin<<<(N + 31) / 32, 256, 0, stream>>>(x, lin_w, att_s, att_d, h2, asrc, adst, N);
    int nbin = (E + BIN_TILE - 1) / BIN_TILE;
    k_b0<<<nbin, 256, 0, stream>>>(ei, E, bcnt, NB);
    k_bscan<<<1, 1024, 0, stream>>>(bcnt, bbase, bcur, NB, E);
    k_bin<<<nbin, 256, 0, stream>>>(ei, E, bcur, stage, NB);
    k_bsort<<<NB, 256, 0, stream>>>(bbase, stage, rowptr, csr, N, E);
    k_agg<<<(N + 3) / 4, 256, 0, stream>>>(rowptr, csr, h2, asrc, adst, bias, batch, pooled, N);
    k_bnstat<<<1, 512, 0, stream>>>(pooled, gamma, beta, scale, shift, G);
    k_fc<<<G, 128, 0, stream>>>(pooled, scale, shift, fcw, fcb, out, LAT);
}

// Round 8
// 269.384 us; speedup vs baseline: 2.9226x; 1.1729x over previous
//
#include <hip/hip_runtime.h>
#include <hip/hip_bf16.h>

// GAT via 2-level bucketed CSR build (LDS-binned counting sort). h = x@W^T
// stored bf16 (k_lin register-tiled 8rows x 2cols, LDS-lean); att coeffs fused
// into k_lin epilogue; k_agg is edge-parallel: lanes own edges (exp once/edge),
// 4-deep pipelined bf16 row gathers, fused graph-pool atomics; BN; FC.
// H=2 heads x C=64.  Softmax max-shift skipped (|e| small, exp safe in fp32).
// NOTE: all __shfl/ds_bpermute ops MUST run with full exec (convergent) —
// never inside a divergent ternary/branch. Broadcast both heads, then select.

#define BKT_SHIFT 8              // 256 nodes per bucket
#define BKT_MASK  255
#define BKT_CAP   14336          // LDS staging records in k_bsort (56 KB)
#define BIN_TILE  4096           // edges per block in k_b0/k_bin

static __device__ __forceinline__ float bf2f(unsigned short u) {
    union { unsigned int i; float f; } c; c.i = ((unsigned int)u) << 16; return c.f;
}
static __device__ __forceinline__ unsigned short f2bf(float f) {
    unsigned int b = __builtin_bit_cast(unsigned int, f);
    return (unsigned short)((b >> 16) + ((b >> 15) & 1));
}

// ---------------- zero fill ----------------
__global__ void k_zero(float* __restrict__ p, long long n) {
    long long i = (long long)blockIdx.x * blockDim.x + threadIdx.x;
    long long stride = (long long)gridDim.x * blockDim.x;
    for (; i < n; i += stride) p[i] = 0.f;
}

// ------- h = x @ W^T -> bf16 h2; fused a_src/a_dst (fp32, wave-reduced) -------
// Per-thread tile: 8 rows x 2 cols (j=lane head0, j+64 head1).
// xl reads are wave-uniform b128 broadcasts; wl reads rotated b32 (2-way max).
__global__ __launch_bounds__(256) void k_lin(const float* __restrict__ x,
                                             const float* __restrict__ w,
                                             const float* __restrict__ att_s,
                                             const float* __restrict__ att_d,
                                             unsigned short* __restrict__ h2,
                                             float* __restrict__ asrc,
                                             float* __restrict__ adst, int N) {
    __shared__ float wl[128 * 64];   // wl[j*64 + ((kk + j) & 63)]
    __shared__ float xl[32 * 128];
    const int t = threadIdx.x;
    const int row0 = blockIdx.x * 32;
    const int lane = t & 63;         // col j = lane (head0), lane+64 (head1)
    const int r0 = (t >> 6) * 8;     // 8 local rows per wave

    for (int i = t; i < 32 * 128; i += 256) {
        int r = row0 + (i >> 7);
        xl[i] = (r < N) ? x[(long long)r * 128 + (i & 127)] : 0.f;
    }

    float acc0[8], acc1[8];
#pragma unroll
    for (int r = 0; r < 8; ++r) { acc0[r] = 0.f; acc1[r] = 0.f; }

    for (int half = 0; half < 2; ++half) {
        __syncthreads();
        for (int i = t; i < 128 * 64; i += 256) {
            int jj = i >> 6, kk = i & 63;
            wl[jj * 64 + ((kk + jj) & 63)] = w[jj * 128 + half * 64 + kk];
        }
        __syncthreads();
        const int kb = half * 64;
        for (int kk = 0; kk < 64; kk += 4) {
            float w0v[4], w1v[4];
#pragma unroll
            for (int q = 0; q < 4; ++q) {
                int rot = (kk + q + lane) & 63;
                w0v[q] = wl[lane * 64 + rot];
                w1v[q] = wl[(lane + 64) * 64 + rot];
            }
#pragma unroll
            for (int r = 0; r < 8; ++r) {
                float4 xv = *(const float4*)&xl[(r0 + r) * 128 + kb + kk];
                acc0[r] = fmaf(xv.x, w0v[0], acc0[r]);
                acc0[r] = fmaf(xv.y, w0v[1], acc0[r]);
                acc0[r] = fmaf(xv.z, w0v[2], acc0[r]);
                acc0[r] = fmaf(xv.w, w0v[3], acc0[r]);
                acc1[r] = fmaf(xv.x, w1v[0], acc1[r]);
                acc1[r] = fmaf(xv.y, w1v[1], acc1[r]);
                acc1[r] = fmaf(xv.z, w1v[2], acc1[r]);
                acc1[r] = fmaf(xv.w, w1v[3], acc1[r]);
            }
        }
    }

    const float as0 = att_s[lane], as1 = att_s[lane + 64];
    const float ad0 = att_d[lane], ad1 = att_d[lane + 64];
#pragma unroll
    for (int r = 0; r < 8; ++r) {
        int row = row0 + r0 + r;
        bool ok = row < N;
        if (ok) {
            h2[(long long)row * 128 + lane]      = f2bf(acc0[r]);
            h2[(long long)row * 128 + 64 + lane] = f2bf(acc1[r]);
        }
        float ps0 = acc0[r] * as0, pd0 = acc0[r] * ad0;
        float ps1 = acc1[r] * as1, pd1 = acc1[r] * ad1;
#pragma unroll
        for (int off = 32; off; off >>= 1) {
            ps0 += __shfl_xor(ps0, off);
            pd0 += __shfl_xor(pd0, off);
            ps1 += __shfl_xor(ps1, off);
            pd1 += __shfl_xor(pd1, off);
        }
        if (lane == 0 && ok) {
            asrc[row * 2] = ps0; asrc[row * 2 + 1] = ps1;
            adst[row * 2] = pd0; adst[row * 2 + 1] = pd1;
        }
    }
}

// ------- CSR build A: bucket histogram (one global atomic per block*bucket) ----
__global__ __launch_bounds__(256) void k_b0(const int* __restrict__ ei, int E,
                                            int* __restrict__ bcnt, int NB) {
    __shared__ int cnt[1024];
    int t = threadIdx.x;
    for (int i = t; i < 1024; i += 256) cnt[i] = 0;
    __syncthreads();
    int base = blockIdx.x * BIN_TILE;
    int end = min(base + BIN_TILE, E);
    for (int i = base + t; i < end; i += 256)
        atomicAdd(&cnt[ei[E + i] >> BKT_SHIFT], 1);
    __syncthreads();
    for (int b = t; b < NB; b += 256)
        if (cnt[b]) atomicAdd(&bcnt[b], cnt[b]);
}

// ------- CSR build B: scan bucket counts -> bases & cursors (1 block) ----------
__global__ __launch_bounds__(1024) void k_bscan(const int* __restrict__ bcnt,
                                                int* __restrict__ bbase,
                                                int* __restrict__ bcur, int NB, int E) {
    __shared__ int part[1024];
    int t = threadIdx.x;
    int v = (t < NB) ? bcnt[t] : 0;
    part[t] = v;
    __syncthreads();
    for (int off = 1; off < 1024; off <<= 1) {
        int u = (t >= off) ? part[t - off] : 0;
        __syncthreads();
        part[t] += u;
        __syncthreads();
    }
    if (t < NB) {
        int ex = part[t] - v;
        bbase[t] = ex;
        bcur[t] = ex;
    }
    if (t == 0) bbase[NB] = E;
}

// ------- CSR build C: bin edges into bucket runs (packed dl<<24|src) -----------
__global__ __launch_bounds__(256) void k_bin(const int* __restrict__ ei, int E,
                                             int* __restrict__ bcur,
                                             unsigned int* __restrict__ stage, int NB) {
    __shared__ int cnt[1024];
    __shared__ int gbase[1024];
    int t = threadIdx.x;
    for (int i = t; i < 1024; i += 256) cnt[i] = 0;
    __syncthreads();
    int base = blockIdx.x * BIN_TILE;
    int end = min(base + BIN_TILE, E);
    for (int i = base + t; i < end; i += 256)
        atomicAdd(&cnt[ei[E + i] >> BKT_SHIFT], 1);
    __syncthreads();
    for (int b = t; b < NB; b += 256) {
        int c = cnt[b];
        gbase[b] = c ? atomicAdd(&bcur[b], c) : 0;
    }
    __syncthreads();
    for (int i = t; i < 1024; i += 256) cnt[i] = 0;
    __syncthreads();
    for (int i = base + t; i < end; i += 256) {
        int s = ei[i];
        int d = ei[E + i];
        int b = d >> BKT_SHIFT;
        int off = atomicAdd(&cnt[b], 1);
        stage[gbase[b] + off] = ((unsigned int)(d & BKT_MASK) << 24) | (unsigned int)s;
    }
}

// ------- CSR build D: per-bucket counting sort; emits rowptr AND csr -----------
__global__ __launch_bounds__(256) void k_bsort(const int* __restrict__ bbase,
                                               const unsigned int* __restrict__ stage,
                                               int* __restrict__ rowptr,
                                               int* __restrict__ csr, int N, int E) {
    __shared__ int hist[256];
    __shared__ int sc[256];
    __shared__ int rp[256];
    __shared__ int lc[256];
    __shared__ int lout[BKT_CAP];
    int b = blockIdx.x;
    int node0 = b << BKT_SHIFT;
    int nloc = min(256, N - node0);
    int t = threadIdx.x;
    int bb = bbase[b], be = bbase[b + 1];
    hist[t] = 0; lc[t] = 0;
    __syncthreads();
    for (int i = bb + t; i < be; i += 256)
        atomicAdd(&hist[stage[i] >> 24], 1);
    __syncthreads();
    sc[t] = hist[t];
    __syncthreads();
    for (int off = 1; off < 256; off <<= 1) {
        int u = (t >= off) ? sc[t - off] : 0;
        __syncthreads();
        sc[t] += u;
        __syncthreads();
    }
    int rpg = bb + sc[t] - hist[t];
    rp[t] = rpg;
    if (t < nloc) rowptr[node0 + t] = rpg;
    if (b == 0 && t == 0) rowptr[N] = E;
    __syncthreads();
    for (int i = bb + t; i < be; i += 256) {
        unsigned int wrec = stage[i];
        int dl = (int)(wrec >> 24);
        int src = (int)(wrec & 0x00FFFFFFu);
        int pos = rp[dl] + atomicAdd(&lc[dl], 1);
        int rel = pos - bb;
        if (rel < BKT_CAP) lout[rel] = src;
        else csr[pos] = src;
    }
    __syncthreads();
    int cntb = be - bb; if (cntb > BKT_CAP) cntb = BKT_CAP;
    for (int i = t; i < cntb; i += 256) csr[bb + i] = lout[i];
}

// ------- aggregation: wave per dst; lanes own edges (exp once per edge);
//         4-deep pipelined bf16 row gathers; fused graph-pool atomics -------
__global__ __launch_bounds__(256) void k_agg(const int* __restrict__ rowptr,
                                             const int* __restrict__ csr_src,
                                             const unsigned short* __restrict__ h2,
                                             const float* __restrict__ asrc,
                                             const float* __restrict__ adst,
                                             const float* __restrict__ bias,
                                             const int* __restrict__ batch,
                                             float* __restrict__ pooled, int N) {
    int n = __builtin_amdgcn_readfirstlane(blockIdx.x * 4 + (threadIdx.x >> 6));
    int lane = threadIdx.x & 63;
    if (n >= N) return;

    float2 adn = *(const float2*)(adst + (size_t)n * 2);
    float2 asn = *(const float2*)(asrc + (size_t)n * 2);
    float e0 = asn.x + adn.x; e0 = e0 > 0.f ? e0 : 0.2f * e0;
    float e1 = asn.y + adn.y; e1 = e1 > 0.f ? e1 : 0.2f * e1;
    float w0 = __expf(e0), w1 = __expf(e1);   // self-loop weights

    unsigned int v = *(const unsigned int*)(h2 + (long long)n * 128 + lane * 2);
    float wsel = (lane < 32) ? w0 : w1;
    float accX = wsel * bf2f((unsigned short)(v & 0xffff));
    float accY = wsel * bf2f((unsigned short)(v >> 16));
    float accX2 = 0.f, accY2 = 0.f;
    float ps0 = 0.f, ps1 = 0.f;               // per-lane softmax-denominator partials

    const int beg = rowptr[n], end = rowptr[n + 1];
    const bool lo = (lane < 32);

    for (int base = beg; base < end; base += 64) {
        int cnt = min(64, end - base);
        int sv = 0; float u0 = 0.f, u1 = 0.f;
        if (lane < cnt) {
            sv = csr_src[base + lane];                       // coalesced
            float2 a = *(const float2*)(asrc + (size_t)sv * 2);  // 8B gather
            float f0 = a.x + adn.x; f0 = f0 > 0.f ? f0 : 0.2f * f0;
            float f1 = a.y + adn.y; f1 = f1 > 0.f ? f1 : 0.2f * f1;
            u0 = __expf(f0); u1 = __expf(f1);
        }
        ps0 += u0; ps1 += u1;

        int k = 0;
        for (; k + 4 <= cnt; k += 4) {
            int sA = __builtin_amdgcn_readfirstlane(__shfl(sv, k));
            int sB = __builtin_amdgcn_readfirstlane(__shfl(sv, k + 1));
            int sC = __builtin_amdgcn_readfirstlane(__shfl(sv, k + 2));
            int sD = __builtin_amdgcn_readfirstlane(__shfl(sv, k + 3));
            unsigned int vA = *(const unsigned int*)(h2 + (long long)sA * 128 + lane * 2);
            unsigned int vB = *(const unsigned int*)(h2 + (long long)sB * 128 + lane * 2);
            unsigned int vC = *(const unsigned int*)(h2 + (long long)sC * 128 + lane * 2);
            unsigned int vD = *(const unsigned int*)(h2 + (long long)sD * 128 + lane * 2);
            // CONVERGENT: both-head broadcasts with full exec, THEN value-select.
            float uA0 = __shfl(u0, k),     uA1 = __shfl(u1, k);
            float uB0 = __shfl(u0, k + 1), uB1 = __shfl(u1, k + 1);
            float uC0 = __shfl(u0, k + 2), uC1 = __shfl(u1, k + 2);
            float uD0 = __shfl(u0, k + 3), uD1 = __shfl(u1, k + 3);
            float uA = lo ? uA0 : uA1;
            float uB = lo ? uB0 : uB1;
            float uC = lo ? uC0 : uC1;
            float uD = lo ? uD0 : uD1;
            accX  = fmaf(uA, bf2f((unsigned short)(vA & 0xffff)), accX);
            accY  = fmaf(uA, bf2f((unsigned short)(vA >> 16)),    accY);
            accX2 = fmaf(uB, bf2f((unsigned short)(vB & 0xffff)), accX2);
            accY2 = fmaf(uB, bf2f((unsigned short)(vB >> 16)),    accY2);
            accX  = fmaf(uC, bf2f((unsigned short)(vC & 0xffff)), accX);
            accY  = fmaf(uC, bf2f((unsigned short)(vC >> 16)),    accY);
            accX2 = fmaf(uD, bf2f((unsigned short)(vD & 0xffff)), accX2);
            accY2 = fmaf(uD, bf2f((unsigned short)(vD >> 16)),    accY2);
        }
        for (; k < cnt; ++k) {
            int sA = __builtin_amdgcn_readfirstlane(__shfl(sv, k));
            unsigned int vA = *(const unsigned int*)(h2 + (long long)sA * 128 + lane * 2);
            float uA0 = __shfl(u0, k), uA1 = __shfl(u1, k);
            float uA = lo ? uA0 : uA1;
            accX = fmaf(uA, bf2f((unsigned short)(vA & 0xffff)), accX);
            accY = fmaf(uA, bf2f((unsigned short)(vA >> 16)),    accY);
        }
    }

#pragma unroll
    for (int off = 32; off; off >>= 1) {
        ps0 += __shfl_xor(ps0, off);
        ps1 += __shfl_xor(ps1, off);
    }
    float s0 = ps0 + w0, s1 = ps1 + w1;
    float sdiv = lo ? s0 : s1;
    accX += accX2; accY += accY2;

    int j0 = lane * 2;
    float2 bv = *(const float2*)(bias + j0);
    float o0 = accX / sdiv + bv.x;
    float o1 = accY / sdiv + bv.y;
    int g = batch[n];
    atomicAdd(&pooled[g * 128 + j0], o0);
    atomicAdd(&pooled[g * 128 + j0 + 1], o1);
}

// ---------------- batchnorm stats over G graphs ----------------
__global__ __launch_bounds__(512) void k_bnstat(const float* __restrict__ pooled,
                                                const float* __restrict__ gamma,
                                                const float* __restrict__ beta,
                                                float* __restrict__ scale,
                                                float* __restrict__ shift, int G) {
    __shared__ float ls[512], lq[512];
    int t = threadIdx.x;
    int j = t & 127, q = t >> 7;
    int per = G >> 2;
    float sum = 0.f, sq = 0.f;
    for (int g = q * per; g < (q + 1) * per; ++g) {
        float v = pooled[g * 128 + j];
        sum += v; sq += v * v;
    }
    ls[t] = sum; lq[t] = sq;
    __syncthreads();
    if (t < 128) {
        sum = ls[t] + ls[t + 128] + ls[t + 256] + ls[t + 384];
        sq  = lq[t] + lq[t + 128] + lq[t + 256] + lq[t + 384];
        float mu = sum / (float)G;
        float var = sq / (float)G - mu * mu;
        float sc = gamma[t] * rsqrtf(var + 1e-5f);
        scale[t] = sc;
        shift[t] = beta[t] - mu * sc;
    }
}

// ---------------- norm + FC (block per graph) ----------------
__global__ __launch_bounds__(128) void k_fc(const float* __restrict__ pooled,
                                            const float* __restrict__ scale,
                                            const float* __restrict__ shift,
                                            const float* __restrict__ fcw,
                                            const float* __restrict__ fcb,
                                            float* __restrict__ out, int LAT) {
    __shared__ float nrm[128];
    int g = blockIdx.x;
    int t = threadIdx.x;
    nrm[t] = pooled[g * 128 + t] * scale[t] + shift[t];
    __syncthreads();
    if (t < LAT) {
        float acc = fcb[t];
#pragma unroll 8
        for (int j = 0; j < 128; ++j)
            acc = fmaf(nrm[j], fcw[t * 128 + j], acc);
        out[g * LAT + t] = acc;
    }
}

extern "C" void kernel_launch(void* const* d_in, const int* in_sizes, int n_in,
                              void* d_out, int out_size, void* d_ws, size_t ws_size,
                              hipStream_t stream) {
    const float* x     = (const float*)d_in[0];
    const int*   ei    = (const int*)d_in[1];
    const int*   batch = (const int*)d_in[2];
    const float* lin_w = (const float*)d_in[4];
    const float* att_s = (const float*)d_in[5];
    const float* att_d = (const float*)d_in[6];
    const float* bias  = (const float*)d_in[7];
    const float* gamma = (const float*)d_in[8];
    const float* beta  = (const float*)d_in[9];
    const float* fcw   = (const float*)d_in[10];
    const float* fcb   = (const float*)d_in[11];
    float* out = (float*)d_out;

    const int N   = in_sizes[2];
    const int E   = in_sizes[1] / 2;
    const int LAT = in_sizes[11];
    const int G   = out_size / LAT;
    const int NB  = (N + 255) >> BKT_SHIFT;

    char* ws = (char*)d_ws;
    unsigned short* h2 = (unsigned short*)ws; ws += (size_t)N * 128 * 2;
    float* asrc   = (float*)ws; ws += (size_t)N * 2 * 4;
    float* adst   = (float*)ws; ws += (size_t)N * 2 * 4;
    // zeroed region: bcnt | pooled (contiguous words)
    int*   bcnt   = (int*)ws;   ws += (size_t)NB * 4;
    float* pooled = (float*)ws; ws += (size_t)G * 128 * 4;
    float* scale  = (float*)ws; ws += 128 * 4;
    float* shift  = (float*)ws; ws += 128 * 4;
    int*   bbase  = (int*)ws;   ws += (size_t)(NB + 1) * 4;
    int*   bcur   = (int*)ws;   ws += (size_t)NB * 4;
    int*   rowptr = (int*)ws;   ws += (size_t)(N + 1) * 4;
    unsigned int* stage = (unsigned int*)ws; ws += (size_t)E * 4;
    int*   csr    = (int*)ws;   ws += (size_t)E * 4;

    long long nzero = (long long)NB + (long long)G * 128;
    k_zero<<<256, 256, 0, stream>>>((float*)bcnt, nzero);

    k_lin<<<(N + 31) / 32, 256, 0, stream>>>(x, lin_w, att_s, att_d, h2, asrc, adst, N);
    int nbin = (E + BIN_TILE - 1) / BIN_TILE;
    k_b0<<<nbin, 256, 0, stream>>>(ei, E, bcnt, NB);
    k_bscan<<<1, 1024, 0, stream>>>(bcnt, bbase, bcur, NB, E);
    k_bin<<<nbin, 256, 0, stream>>>(ei, E, bcur, stage, NB);
    k_bsort<<<NB, 256, 0, stream>>>(bbase, stage, rowptr, csr, N, E);
    k_agg<<<(N + 3) / 4, 256, 0, stream>>>(rowptr, csr, h2, asrc, adst, bias, batch, pooled, N);
    k_bnstat<<<1, 512, 0, stream>>>(pooled, gamma, beta, scale, shift, G);
    k_fc<<<G, 128, 0, stream>>>(pooled, scale, shift, fcw, fcb, out, LAT);
}

// Round 9
// 215.405 us; speedup vs baseline: 3.6550x; 1.2506x over previous
//
#include <hip/hip_runtime.h>
#include <hip/hip_bf16.h>

// GAT. h = x@W^T via bf16 MFMA (16x16x32), no LDS: wave owns 16 rows x 128
// cols, A-frags from x (bf16-converted in flight), B-frags from preconverted
// bf16 W; att coeffs reduced from C fragments via convergent shfl_xor.
// CSR by dst via 2-level bucketed counting sort; k_agg edge-parallel with
// fused graph pooling; BN over graphs; FC 128->32.  H=2 x C=64.
// Softmax max-shift skipped (|e| small, exp safe in fp32).
// All __shfl ops run with full exec (convergent) — never in divergent branches.

#define BKT_SHIFT 8              // 256 nodes per bucket
#define BKT_MASK  255
#define BKT_CAP   14336          // LDS staging records in k_bsort (56 KB)
#define BIN_TILE  4096           // edges per block in k_b0/k_bin

typedef __attribute__((ext_vector_type(8))) short bf16x8;
typedef __attribute__((ext_vector_type(4))) float f32x4;

static __device__ __forceinline__ float bf2f(unsigned short u) {
    union { unsigned int i; float f; } c; c.i = ((unsigned int)u) << 16; return c.f;
}
static __device__ __forceinline__ unsigned short f2bf(float f) {
    unsigned int b = __builtin_bit_cast(unsigned int, f);
    return (unsigned short)((b >> 16) + ((b >> 15) & 1));
}

// ---------------- zero fill ----------------
__global__ void k_zero(float* __restrict__ p, long long n) {
    long long i = (long long)blockIdx.x * blockDim.x + threadIdx.x;
    long long stride = (long long)gridDim.x * blockDim.x;
    for (; i < n; i += stride) p[i] = 0.f;
}

// ---------------- W fp32 -> bf16 (once, 16384 elems) ----------------
__global__ void k_wcvt(const float* __restrict__ w, unsigned short* __restrict__ wb) {
    int i = blockIdx.x * 256 + threadIdx.x;
    if (i < 128 * 128) wb[i] = f2bf(w[i]);
}

// ------- h = x @ W^T via MFMA; h2 bf16; fused a_src/a_dst -------
// Wave: 16 rows x 128 cols. A: row=lane&15, k=(lane>>4)*8+j (8 contig bf16).
// B: col=lane&15, k=(lane>>4)*8+j -> 16B loads from wb[col][k..k+7].
// C/D: col=lane&15, row=(lane>>4)*4+reg  [HW-verified m89/m91].
__global__ __launch_bounds__(256) void k_lin(const float* __restrict__ x,
                                             const unsigned short* __restrict__ wb,
                                             const float* __restrict__ att_s,
                                             const float* __restrict__ att_d,
                                             unsigned short* __restrict__ h2,
                                             float* __restrict__ asrc,
                                             float* __restrict__ adst, int N) {
    const int t = threadIdx.x;
    const int lane = t & 63;
    const int wid = t >> 6;
    const int row0 = (blockIdx.x * 4 + wid) * 16;
    const int rlo = lane & 15;       // A-row / B-col / C-col offset
    const int khi = lane >> 4;       // k-chunk / C-row-group

    // A fragments: 4 k-steps of 32, each lane 8 contiguous bf16 from its row
    int arow = row0 + rlo; if (arow >= N) arow = N - 1;   // clamp (stores guarded)
    const float* xrow = x + (long long)arow * 128;
    bf16x8 afrag[4];
#pragma unroll
    for (int ks = 0; ks < 4; ++ks) {
        int k0 = ks * 32 + khi * 8;
        float4 xa = *(const float4*)(xrow + k0);
        float4 xb = *(const float4*)(xrow + k0 + 4);
        bf16x8 a;
        a[0] = (short)f2bf(xa.x); a[1] = (short)f2bf(xa.y);
        a[2] = (short)f2bf(xa.z); a[3] = (short)f2bf(xa.w);
        a[4] = (short)f2bf(xb.x); a[5] = (short)f2bf(xb.y);
        a[6] = (short)f2bf(xb.z); a[7] = (short)f2bf(xb.w);
        afrag[ks] = a;
    }

    float ps0[4] = {0.f,0.f,0.f,0.f}, pd0[4] = {0.f,0.f,0.f,0.f};
    float ps1[4] = {0.f,0.f,0.f,0.f}, pd1[4] = {0.f,0.f,0.f,0.f};

    for (int ct = 0; ct < 8; ++ct) {             // 8 col-tiles of 16
        const int col = ct * 16 + rlo;
        f32x4 acc = {0.f, 0.f, 0.f, 0.f};
#pragma unroll
        for (int ks = 0; ks < 4; ++ks) {
            bf16x8 b = *(const bf16x8*)(wb + (size_t)col * 128 + ks * 32 + khi * 8);
            acc = __builtin_amdgcn_mfma_f32_16x16x32_bf16(afrag[ks], b, acc, 0, 0, 0);
        }
        const float as = att_s[col], ad = att_d[col];
        const bool head0 = (ct < 4);             // wave-uniform
#pragma unroll
        for (int r = 0; r < 4; ++r) {
            int row = row0 + khi * 4 + r;
            if (row < N) h2[(long long)row * 128 + col] = f2bf(acc[r]);
            float v = acc[r];
            if (head0) { ps0[r] = fmaf(v, as, ps0[r]); pd0[r] = fmaf(v, ad, pd0[r]); }
            else       { ps1[r] = fmaf(v, as, ps1[r]); pd1[r] = fmaf(v, ad, pd1[r]); }
        }
    }

    // reduce partials over the 16 cols (rlo) within each khi group — convergent
#pragma unroll
    for (int off = 1; off <= 8; off <<= 1) {
#pragma unroll
        for (int r = 0; r < 4; ++r) {
            ps0[r] += __shfl_xor(ps0[r], off);
            pd0[r] += __shfl_xor(pd0[r], off);
            ps1[r] += __shfl_xor(ps1[r], off);
            pd1[r] += __shfl_xor(pd1[r], off);
        }
    }
    if (rlo == 0) {
#pragma unroll
        for (int r = 0; r < 4; ++r) {
            int row = row0 + khi * 4 + r;
            if (row < N) {
                asrc[row * 2]     = ps0[r];
                asrc[row * 2 + 1] = ps1[r];
                adst[row * 2]     = pd0[r];
                adst[row * 2 + 1] = pd1[r];
            }
        }
    }
}

// ------- CSR build A: bucket histogram (one global atomic per block*bucket) ----
__global__ __launch_bounds__(256) void k_b0(const int* __restrict__ ei, int E,
                                            int* __restrict__ bcnt, int NB) {
    __shared__ int cnt[1024];
    int t = threadIdx.x;
    for (int i = t; i < 1024; i += 256) cnt[i] = 0;
    __syncthreads();
    int base = blockIdx.x * BIN_TILE;
    int end = min(base + BIN_TILE, E);
    for (int i = base + t; i < end; i += 256)
        atomicAdd(&cnt[ei[E + i] >> BKT_SHIFT], 1);
    __syncthreads();
    for (int b = t; b < NB; b += 256)
        if (cnt[b]) atomicAdd(&bcnt[b], cnt[b]);
}

// ------- CSR build B: scan bucket counts -> bases & cursors (1 block) ----------
__global__ __launch_bounds__(1024) void k_bscan(const int* __restrict__ bcnt,
                                                int* __restrict__ bbase,
                                                int* __restrict__ bcur, int NB, int E) {
    __shared__ int part[1024];
    int t = threadIdx.x;
    int v = (t < NB) ? bcnt[t] : 0;
    part[t] = v;
    __syncthreads();
    for (int off = 1; off < 1024; off <<= 1) {
        int u = (t >= off) ? part[t - off] : 0;
        __syncthreads();
        part[t] += u;
        __syncthreads();
    }
    if (t < NB) {
        int ex = part[t] - v;
        bbase[t] = ex;
        bcur[t] = ex;
    }
    if (t == 0) bbase[NB] = E;
}

// ------- CSR build C: bin edges into bucket runs (packed dl<<24|src) -----------
__global__ __launch_bounds__(256) void k_bin(const int* __restrict__ ei, int E,
                                             int* __restrict__ bcur,
                                             unsigned int* __restrict__ stage, int NB) {
    __shared__ int cnt[1024];
    __shared__ int gbase[1024];
    int t = threadIdx.x;
    for (int i = t; i < 1024; i += 256) cnt[i] = 0;
    __syncthreads();
    int base = blockIdx.x * BIN_TILE;
    int end = min(base + BIN_TILE, E);
    for (int i = base + t; i < end; i += 256)
        atomicAdd(&cnt[ei[E + i] >> BKT_SHIFT], 1);
    __syncthreads();
    for (int b = t; b < NB; b += 256) {
        int c = cnt[b];
        gbase[b] = c ? atomicAdd(&bcur[b], c) : 0;
    }
    __syncthreads();
    for (int i = t; i < 1024; i += 256) cnt[i] = 0;
    __syncthreads();
    for (int i = base + t; i < end; i += 256) {
        int s = ei[i];
        int d = ei[E + i];
        int b = d >> BKT_SHIFT;
        int off = atomicAdd(&cnt[b], 1);
        stage[gbase[b] + off] = ((unsigned int)(d & BKT_MASK) << 24) | (unsigned int)s;
    }
}

// ------- CSR build D: per-bucket counting sort; emits rowptr AND csr -----------
__global__ __launch_bounds__(256) void k_bsort(const int* __restrict__ bbase,
                                               const unsigned int* __restrict__ stage,
                                               int* __restrict__ rowptr,
                                               int* __restrict__ csr, int N, int E) {
    __shared__ int hist[256];
    __shared__ int sc[256];
    __shared__ int rp[256];
    __shared__ int lc[256];
    __shared__ int lout[BKT_CAP];
    int b = blockIdx.x;
    int node0 = b << BKT_SHIFT;
    int nloc = min(256, N - node0);
    int t = threadIdx.x;
    int bb = bbase[b], be = bbase[b + 1];
    hist[t] = 0; lc[t] = 0;
    __syncthreads();
    for (int i = bb + t; i < be; i += 256)
        atomicAdd(&hist[stage[i] >> 24], 1);
    __syncthreads();
    sc[t] = hist[t];
    __syncthreads();
    for (int off = 1; off < 256; off <<= 1) {
        int u = (t >= off) ? sc[t - off] : 0;
        __syncthreads();
        sc[t] += u;
        __syncthreads();
    }
    int rpg = bb + sc[t] - hist[t];
    rp[t] = rpg;
    if (t < nloc) rowptr[node0 + t] = rpg;
    if (b == 0 && t == 0) rowptr[N] = E;
    __syncthreads();
    for (int i = bb + t; i < be; i += 256) {
        unsigned int wrec = stage[i];
        int dl = (int)(wrec >> 24);
        int src = (int)(wrec & 0x00FFFFFFu);
        int pos = rp[dl] + atomicAdd(&lc[dl], 1);
        int rel = pos - bb;
        if (rel < BKT_CAP) lout[rel] = src;
        else csr[pos] = src;
    }
    __syncthreads();
    int cntb = be - bb; if (cntb > BKT_CAP) cntb = BKT_CAP;
    for (int i = t; i < cntb; i += 256) csr[bb + i] = lout[i];
}

// ------- aggregation: wave per dst; lanes own edges (exp once per edge);
//         4-deep pipelined bf16 row gathers; fused graph-pool atomics -------
__global__ __launch_bounds__(256) void k_agg(const int* __restrict__ rowptr,
                                             const int* __restrict__ csr_src,
                                             const unsigned short* __restrict__ h2,
                                             const float* __restrict__ asrc,
                                             const float* __restrict__ adst,
                                             const float* __restrict__ bias,
                                             const int* __restrict__ batch,
                                             float* __restrict__ pooled, int N) {
    int n = __builtin_amdgcn_readfirstlane(blockIdx.x * 4 + (threadIdx.x >> 6));
    int lane = threadIdx.x & 63;
    if (n >= N) return;

    float2 adn = *(const float2*)(adst + (size_t)n * 2);
    float2 asn = *(const float2*)(asrc + (size_t)n * 2);
    float e0 = asn.x + adn.x; e0 = e0 > 0.f ? e0 : 0.2f * e0;
    float e1 = asn.y + adn.y; e1 = e1 > 0.f ? e1 : 0.2f * e1;
    float w0 = __expf(e0), w1 = __expf(e1);   // self-loop weights

    unsigned int v = *(const unsigned int*)(h2 + (long long)n * 128 + lane * 2);
    float wsel = (lane < 32) ? w0 : w1;
    float accX = wsel * bf2f((unsigned short)(v & 0xffff));
    float accY = wsel * bf2f((unsigned short)(v >> 16));
    float accX2 = 0.f, accY2 = 0.f;
    float ps0 = 0.f, ps1 = 0.f;

    const int beg = rowptr[n], end = rowptr[n + 1];
    const bool lo = (lane < 32);

    for (int base = beg; base < end; base += 64) {
        int cnt = min(64, end - base);
        int sv = 0; float u0 = 0.f, u1 = 0.f;
        if (lane < cnt) {
            sv = csr_src[base + lane];
            float2 a = *(const float2*)(asrc + (size_t)sv * 2);
            float f0 = a.x + adn.x; f0 = f0 > 0.f ? f0 : 0.2f * f0;
            float f1 = a.y + adn.y; f1 = f1 > 0.f ? f1 : 0.2f * f1;
            u0 = __expf(f0); u1 = __expf(f1);
        }
        ps0 += u0; ps1 += u1;

        int k = 0;
        for (; k + 4 <= cnt; k += 4) {
            int sA = __builtin_amdgcn_readfirstlane(__shfl(sv, k));
            int sB = __builtin_amdgcn_readfirstlane(__shfl(sv, k + 1));
            int sC = __builtin_amdgcn_readfirstlane(__shfl(sv, k + 2));
            int sD = __builtin_amdgcn_readfirstlane(__shfl(sv, k + 3));
            unsigned int vA = *(const unsigned int*)(h2 + (long long)sA * 128 + lane * 2);
            unsigned int vB = *(const unsigned int*)(h2 + (long long)sB * 128 + lane * 2);
            unsigned int vC = *(const unsigned int*)(h2 + (long long)sC * 128 + lane * 2);
            unsigned int vD = *(const unsigned int*)(h2 + (long long)sD * 128 + lane * 2);
            float uA0 = __shfl(u0, k),     uA1 = __shfl(u1, k);
            float uB0 = __shfl(u0, k + 1), uB1 = __shfl(u1, k + 1);
            float uC0 = __shfl(u0, k + 2), uC1 = __shfl(u1, k + 2);
            float uD0 = __shfl(u0, k + 3), uD1 = __shfl(u1, k + 3);
            float uA = lo ? uA0 : uA1;
            float uB = lo ? uB0 : uB1;
            float uC = lo ? uC0 : uC1;
            float uD = lo ? uD0 : uD1;
            accX  = fmaf(uA, bf2f((unsigned short)(vA & 0xffff)), accX);
            accY  = fmaf(uA, bf2f((unsigned short)(vA >> 16)),    accY);
            accX2 = fmaf(uB, bf2f((unsigned short)(vB & 0xffff)), accX2);
            accY2 = fmaf(uB, bf2f((unsigned short)(vB >> 16)),    accY2);
            accX  = fmaf(uC, bf2f((unsigned short)(vC & 0xffff)), accX);
            accY  = fmaf(uC, bf2f((unsigned short)(vC >> 16)),    accY);
            accX2 = fmaf(uD, bf2f((unsigned short)(vD & 0xffff)), accX2);
            accY2 = fmaf(uD, bf2f((unsigned short)(vD >> 16)),    accY2);
        }
        for (; k < cnt; ++k) {
            int sA = __builtin_amdgcn_readfirstlane(__shfl(sv, k));
            unsigned int vA = *(const unsigned int*)(h2 + (long long)sA * 128 + lane * 2);
            float uA0 = __shfl(u0, k), uA1 = __shfl(u1, k);
            float uA = lo ? uA0 : uA1;
            accX = fmaf(uA, bf2f((unsigned short)(vA & 0xffff)), accX);
            accY = fmaf(uA, bf2f((unsigned short)(vA >> 16)),    accY);
        }
    }

#pragma unroll
    for (int off = 32; off; off >>= 1) {
        ps0 += __shfl_xor(ps0, off);
        ps1 += __shfl_xor(ps1, off);
    }
    float s0 = ps0 + w0, s1 = ps1 + w1;
    float sdiv = lo ? s0 : s1;
    accX += accX2; accY += accY2;

    int j0 = lane * 2;
    float2 bv = *(const float2*)(bias + j0);
    float o0 = accX / sdiv + bv.x;
    float o1 = accY / sdiv + bv.y;
    int g = batch[n];
    atomicAdd(&pooled[g * 128 + j0], o0);
    atomicAdd(&pooled[g * 128 + j0 + 1], o1);
}

// ---------------- batchnorm stats over G graphs ----------------
__global__ __launch_bounds__(512) void k_bnstat(const float* __restrict__ pooled,
                                                const float* __restrict__ gamma,
                                                const float* __restrict__ beta,
                                                float* __restrict__ scale,
                                                float* __restrict__ shift, int G) {
    __shared__ float ls[512], lq[512];
    int t = threadIdx.x;
    int j = t & 127, q = t >> 7;
    int per = G >> 2;
    float sum = 0.f, sq = 0.f;
    for (int g = q * per; g < (q + 1) * per; ++g) {
        float v = pooled[g * 128 + j];
        sum += v; sq += v * v;
    }
    ls[t] = sum; lq[t] = sq;
    __syncthreads();
    if (t < 128) {
        sum = ls[t] + ls[t + 128] + ls[t + 256] + ls[t + 384];
        sq  = lq[t] + lq[t + 128] + lq[t + 256] + lq[t + 384];
        float mu = sum / (float)G;
        float var = sq / (float)G - mu * mu;
        float sc = gamma[t] * rsqrtf(var + 1e-5f);
        scale[t] = sc;
        shift[t] = beta[t] - mu * sc;
    }
}

// ---------------- norm + FC (block per graph) ----------------
__global__ __launch_bounds__(128) void k_fc(const float* __restrict__ pooled,
                                            const float* __restrict__ scale,
                                            const float* __restrict__ shift,
                                            const float* __restrict__ fcw,
                                            const float* __restrict__ fcb,
                                            float* __restrict__ out, int LAT) {
    __shared__ float nrm[128];
    int g = blockIdx.x;
    int t = threadIdx.x;
    nrm[t] = pooled[g * 128 + t] * scale[t] + shift[t];
    __syncthreads();
    if (t < LAT) {
        float acc = fcb[t];
#pragma unroll 8
        for (int j = 0; j < 128; ++j)
            acc = fmaf(nrm[j], fcw[t * 128 + j], acc);
        out[g * LAT + t] = acc;
    }
}

extern "C" void kernel_launch(void* const* d_in, const int* in_sizes, int n_in,
                              void* d_out, int out_size, void* d_ws, size_t ws_size,
                              hipStream_t stream) {
    const float* x     = (const float*)d_in[0];
    const int*   ei    = (const int*)d_in[1];
    const int*   batch = (const int*)d_in[2];
    const float* lin_w = (const float*)d_in[4];
    const float* att_s = (const float*)d_in[5];
    const float* att_d = (const float*)d_in[6];
    const float* bias  = (const float*)d_in[7];
    const float* gamma = (const float*)d_in[8];
    const float* beta  = (const float*)d_in[9];
    const float* fcw   = (const float*)d_in[10];
    const float* fcb   = (const float*)d_in[11];
    float* out = (float*)d_out;

    const int N   = in_sizes[2];
    const int E   = in_sizes[1] / 2;
    const int LAT = in_sizes[11];
    const int G   = out_size / LAT;
    const int NB  = (N + 255) >> BKT_SHIFT;

    char* ws = (char*)d_ws;
    unsigned short* h2 = (unsigned short*)ws; ws += (size_t)N * 128 * 2;
    unsigned short* wb = (unsigned short*)ws; ws += (size_t)128 * 128 * 2;
    float* asrc   = (float*)ws; ws += (size_t)N * 2 * 4;
    float* adst   = (float*)ws; ws += (size_t)N * 2 * 4;
    // zeroed region: bcnt | pooled (contiguous words)
    int*   bcnt   = (int*)ws;   ws += (size_t)NB * 4;
    float* pooled = (float*)ws; ws += (size_t)G * 128 * 4;
    float* scale  = (float*)ws; ws += 128 * 4;
    float* shift  = (float*)ws; ws += 128 * 4;
    int*   bbase  = (int*)ws;   ws += (size_t)(NB + 1) * 4;
    int*   bcur   = (int*)ws;   ws += (size_t)NB * 4;
    int*   rowptr = (int*)ws;   ws += (size_t)(N + 1) * 4;
    unsigned int* stage = (unsigned int*)ws; ws += (size_t)E * 4;
    int*   csr    = (int*)ws;   ws += (size_t)E * 4;

    long long nzero = (long long)NB + (long long)G * 128;
    k_zero<<<256, 256, 0, stream>>>((float*)bcnt, nzero);
    k_wcvt<<<64, 256, 0, stream>>>(lin_w, wb);

    k_lin<<<(N + 63) / 64, 256, 0, stream>>>(x, wb, att_s, att_d, h2, asrc, adst, N);
    int nbin = (E + BIN_TILE - 1) / BIN_TILE;
    k_b0<<<nbin, 256, 0, stream>>>(ei, E, bcnt, NB);
    k_bscan<<<1, 1024, 0, stream>>>(bcnt, bbase, bcur, NB, E);
    k_bin<<<nbin, 256, 0, stream>>>(ei, E, bcur, stage, NB);
    k_bsort<<<NB, 256, 0, stream>>>(bbase, stage, rowptr, csr, N, E);
    k_agg<<<(N + 3) / 4, 256, 0, stream>>>(rowptr, csr, h2, asrc, adst, bias, batch, pooled, N);
    k_bnstat<<<1, 512, 0, stream>>>(pooled, gamma, beta, scale, shift, G);
    k_fc<<<G, 128, 0, stream>>>(pooled, scale, shift, fcw, fcb, out, LAT);
}